// Round 8
// baseline (995.013 us; speedup 1.0000x reference)
//
#include <hip/hip_runtime.h>
#include <hip/hip_bf16.h>

typedef __attribute__((ext_vector_type(8))) __bf16 bf16x8;
typedef __attribute__((ext_vector_type(4))) float f32x4;

#define NTOK 8192
#define D_DIM 1024
#define F_DIM 4096
#define NEXP 8
#define SLOT_TOT 16384          // 2 * NTOK
#define SLOT_CAP 16640          // SLOT_TOT + 256 padding
#define MT_MAX 32               // worst-case m-tiles per expert (8192/... cnt<=8192 -> 64? no: cnt_e <= NTOK=8192 -> 8192/128=64) -- see note below

// NOTE: a single expert can in principle receive up to NTOK tokens (all top-2
// mass on one expert). cnt_e <= NTOK = 8192 -> up to 64 m-tiles of 128.
#undef MT_MAX
#define MT_MAX 64

__device__ __forceinline__ unsigned short f2b(float f) {
  __hip_bfloat16 b = __float2bfloat16(f);
  return reinterpret_cast<unsigned short&>(b);
}

// tanh-form GELU (branch-free): max |err| vs exact erf-GELU ~3e-4.
__device__ __forceinline__ float gelu_f(float v) {
  const float y2 = v * (1.5957691216f + 0.0713548162f * v * v);
  return v * __builtin_amdgcn_rcpf(1.f + __expf(-y2));
}

__device__ __forceinline__ void gload_lds16(const void* g, void* l) {
  __builtin_amdgcn_global_load_lds(
      (__attribute__((address_space(1))) void*)g,
      (__attribute__((address_space(3))) void*)l, 16, 0, 0);
}

// ---------------- small kernels ----------------

__global__ void init_counts_kernel(int* counts) {
  if (threadIdx.x < NEXP) counts[threadIdx.x] = 0;
}

__global__ void zero_out_kernel(float* out) {
  const int i = blockIdx.x * 256 + threadIdx.x;
  reinterpret_cast<float4*>(out)[i] = make_float4(0.f, 0.f, 0.f, 0.f);
}

// gather x rows into slot order, f32 -> bf16. one block per slot row.
__global__ void gather_x_kernel(const float* __restrict__ x,
                                const int* __restrict__ slot_token,
                                __hip_bfloat16* __restrict__ xg) {
  const int s = blockIdx.x;
  const int t = slot_token[s];
  const int d = threadIdx.x * 4;
  const float4 v = *reinterpret_cast<const float4*>(x + (size_t)t * D_DIM + d);
  union { unsigned short u[4]; uint2 q; } o;
  o.u[0] = f2b(v.x); o.u[1] = f2b(v.y); o.u[2] = f2b(v.z); o.u[3] = f2b(v.w);
  *reinterpret_cast<uint2*>(xg + (size_t)s * D_DIM + d) = o.q;
}

// out[tok] = w0 * ys[s0] + w1 * ys[s1]   (bias already inside ys)
__global__ void combine_kernel(const __hip_bfloat16* __restrict__ ys,
                               const int* __restrict__ slot_pos,
                               const float* __restrict__ topk_w,
                               float* __restrict__ out) {
  const int tok = blockIdx.x;
  const int d = threadIdx.x * 4;
  const int s0 = slot_pos[tok * 2], s1 = slot_pos[tok * 2 + 1];
  const float w0 = topk_w[tok * 2], w1 = topk_w[tok * 2 + 1];
  union { unsigned short u[4]; uint2 q; } a, b;
  a.q = *reinterpret_cast<const uint2*>(ys + (size_t)s0 * D_DIM + d);
  b.q = *reinterpret_cast<const uint2*>(ys + (size_t)s1 * D_DIM + d);
  float4 rr;
  float va[4];
  #pragma unroll
  for (int i = 0; i < 4; ++i) {
    unsigned int ua = (unsigned int)a.u[i] << 16;
    unsigned int ub = (unsigned int)b.u[i] << 16;
    va[i] = w0 * reinterpret_cast<float&>(ua) + w1 * reinterpret_cast<float&>(ub);
  }
  rr.x = va[0]; rr.y = va[1]; rr.z = va[2]; rr.w = va[3];
  *reinterpret_cast<float4*>(out + (size_t)tok * D_DIM + d) = rr;
}

// src: per-expert [R][C] f32  ->  dst: per-expert [C][R] bf16
__global__ void transpose_conv_kernel(const float* __restrict__ src,
                                      __hip_bfloat16* __restrict__ dst,
                                      int R, int C) {
  __shared__ float tile[64][65];
  const int e = blockIdx.z;
  src += (size_t)e * R * C;
  dst += (size_t)e * R * C;
  const int c0 = blockIdx.x * 64, r0 = blockIdx.y * 64;
  const int tx = threadIdx.x, ty = threadIdx.y;   // (16, 16)
  #pragma unroll
  for (int j = 0; j < 4; ++j) {
    const float4 v = *reinterpret_cast<const float4*>(
        &src[(size_t)(r0 + ty + j * 16) * C + c0 + tx * 4]);
    tile[ty + j * 16][tx * 4 + 0] = v.x;
    tile[ty + j * 16][tx * 4 + 1] = v.y;
    tile[ty + j * 16][tx * 4 + 2] = v.z;
    tile[ty + j * 16][tx * 4 + 3] = v.w;
  }
  __syncthreads();
  #pragma unroll
  for (int j = 0; j < 4; ++j) {
    const int c = ty + j * 16;
    union { unsigned short u[4]; uint2 d; } o;
    #pragma unroll
    for (int i = 0; i < 4; ++i) o.u[i] = f2b(tile[tx * 4 + i][c]);
    *reinterpret_cast<uint2*>(&dst[(size_t)(c0 + c) * R + r0 + tx * 4]) = o.d;
  }
}

// ---------------- router ----------------
__global__ void router_kernel(const float* __restrict__ x,
                              const float* __restrict__ rw,
                              const float* __restrict__ rb,
                              int* __restrict__ topk_idx,
                              float* __restrict__ topk_w,
                              int* __restrict__ counts) {
  __shared__ float rwT[NEXP * D_DIM];   // transposed [e][d], 32 KB
  const int tid = threadIdx.x;
  for (int i = tid; i < NEXP * D_DIM; i += 256) {
    const int d = i >> 3, e = i & 7;
    rwT[e * D_DIM + d] = rw[i];
  }
  __syncthreads();

  const int wave = tid >> 6, lane = tid & 63;
  const int tok = blockIdx.x * 4 + wave;
  const float* xr = x + (size_t)tok * D_DIM;

  float acc[NEXP];
  #pragma unroll
  for (int e = 0; e < NEXP; ++e) acc[e] = 0.f;

  for (int i = 0; i < D_DIM / 64; ++i) {
    const int d = i * 64 + lane;
    const float xv = xr[d];
    #pragma unroll
    for (int e = 0; e < NEXP; ++e) acc[e] += xv * rwT[e * D_DIM + d];
  }
  #pragma unroll
  for (int off = 32; off > 0; off >>= 1) {
    #pragma unroll
    for (int e = 0; e < NEXP; ++e) acc[e] += __shfl_xor(acc[e], off);
  }

  if (lane == 0) {
    float l[NEXP];
    #pragma unroll
    for (int e = 0; e < NEXP; ++e) l[e] = acc[e] + rb[e];
    int i1 = 0;
    #pragma unroll
    for (int e = 1; e < NEXP; ++e) if (l[e] > l[i1]) i1 = e;
    int i2 = (i1 == 0) ? 1 : 0;
    #pragma unroll
    for (int e = 0; e < NEXP; ++e) if (e != i1 && e != i2 && l[e] > l[i2]) i2 = e;
    const float w1 = 1.f / (1.f + __expf(l[i2] - l[i1]));
    topk_idx[tok * 2 + 0] = i1;
    topk_idx[tok * 2 + 1] = i2;
    topk_w[tok * 2 + 0] = w1;
    topk_w[tok * 2 + 1] = 1.f - w1;
    atomicAdd(&counts[i1], 1);
    atomicAdd(&counts[i2], 1);
  }
}

__global__ void offsets_kernel(const int* __restrict__ counts,
                               int* __restrict__ offsets,
                               int* __restrict__ cursors,
                               int* __restrict__ slot_token) {
  const int t = threadIdx.x;
  if (t == 0) {
    int s = 0;
    for (int e = 0; e < NEXP; ++e) { offsets[e] = s; cursors[e] = s; s += counts[e]; }
    offsets[NEXP] = s;
  }
  if (t < SLOT_CAP - SLOT_TOT) {   // padding tail reads token 0
    slot_token[SLOT_TOT + t] = 0;
  }
}

__global__ void scatter_kernel(const int* __restrict__ topk_idx,
                               int* __restrict__ cursors,
                               int* __restrict__ slot_token,
                               int* __restrict__ slot_pos) {
  const int tok = blockIdx.x * 256 + threadIdx.x;
  if (tok >= NTOK) return;
  #pragma unroll
  for (int k = 0; k < 2; ++k) {
    const int e = topk_idx[tok * 2 + k];
    const int p = atomicAdd(&cursors[e], 1);
    slot_token[p] = tok;
    slot_pos[tok * 2 + k] = p;
  }
}

// ---------------- MFMA GEMMs ----------------
// 128x128 tile, BK=32, 4 waves (2Mx2N, wave tile 64x64, acc[4][4]).
// Ring-3 LDS (3 x 16 KB = 48 KB) -> 3 blocks/CU (144/160 KB), depth-2
// prefetch: cover ~2 K-step rounds (~1860 cyc) > HBM miss latency (~900).
// Counted vmcnt: steady 12 loads/wave outstanding, wait vmcnt(8) (tile t's
// 4 oldest retired, NEVER 0 in loop); tail peels 4 -> 0. Two s_barriers per
// K-step (pre-compute: all waves' stages landed; post-compute: buf free).
// Expert->XCD pinning: bid = slot*8 + e (round-robin XCD = e); within an
// expert, GEMM1 walks mt fastest (expert's ~4 MB A panel stays L2-resident
// per nt column), GEMM2 walks nt fastest (concurrent blocks share A panel).
// Dead blocks (slot beyond expert's tile count) exit immediately.
template <int PHASE>
__global__ __launch_bounds__(256, 3) void moe_gemm(
    const __hip_bfloat16* __restrict__ A,   // [SLOT_CAP][K] slot-ordered
    const __hip_bfloat16* __restrict__ B,   // [NEXP][NCOL][K]
    const float* __restrict__ bias,         // [NEXP][NCOL]
    const int* __restrict__ counts,
    const int* __restrict__ offsets,
    __hip_bfloat16* __restrict__ Cout) {    // [SLOT_CAP][NCOL]
  constexpr int K    = (PHASE == 1) ? D_DIM : F_DIM;
  constexpr int NCOL = (PHASE == 1) ? F_DIM : D_DIM;
  constexpr int NT   = NCOL / 128;
  constexpr int KT   = K / 32;

  const int bid = blockIdx.x;
  const int e = bid & 7;
  const int slot = bid >> 3;
  int mt, nt;
  if constexpr (PHASE == 1) { mt = slot & (MT_MAX - 1); nt = slot >> 6; }  // mt-fastest
  else                      { nt = slot & (NT - 1);     mt = slot >> 3; }  // nt-fastest
  const int cnt = counts[e];
  if (mt * 128 >= cnt) return;
  const int base = offsets[e];

  __shared__ unsigned short lds[3][8192];   // per buf: A [0,4096) | B [4096,8192) shorts

  const int tid = threadIdx.x;
  const int w = tid >> 6, lane = tid & 63;
  const int r = lane & 15, kg = lane >> 4;
  const int wm = w >> 1, wn = w & 1;

  // wave w stages A chunks {w, w+4} and B chunks {w, w+4}
  const __hip_bfloat16* gA0 = A + (size_t)(base + mt * 128 + w * 16 + r) * K + kg * 8;
  const __hip_bfloat16* gA1 = gA0 + (size_t)64 * K;
  const __hip_bfloat16* gB0 = B + ((size_t)e * NCOL + nt * 128 + w * 16 + r) * K + kg * 8;
  const __hip_bfloat16* gB1 = gB0 + (size_t)64 * K;

  f32x4 acc[4][4] = {};

  auto stage = [&](unsigned short* buf) {
    gload_lds16(gA0, buf + w * 512);
    gload_lds16(gA1, buf + (w + 4) * 512);
    gload_lds16(gB0, buf + 4096 + w * 512);
    gload_lds16(gB1, buf + 4096 + (w + 4) * 512);
    gA0 += 32; gA1 += 32; gB0 += 32; gB1 += 32;
  };
  auto compute = [&](const unsigned short* buf) {
    bf16x8 af[4], bfr[4];
    #pragma unroll
    for (int i2 = 0; i2 < 4; ++i2) {
      af[i2]  = *(const bf16x8*)(buf + (wm * 4 + i2) * 512 + lane * 8);
      bfr[i2] = *(const bf16x8*)(buf + 4096 + (wn * 4 + i2) * 512 + lane * 8);
    }
    __builtin_amdgcn_s_setprio(1);
    #pragma unroll
    for (int mi = 0; mi < 4; ++mi)
      #pragma unroll
      for (int ni = 0; ni < 4; ++ni)
        acc[mi][ni] = __builtin_amdgcn_mfma_f32_16x16x32_bf16(
            af[mi], bfr[ni], acc[mi][ni], 0, 0, 0);
    __builtin_amdgcn_s_setprio(0);
  };

  unsigned short *p0 = lds[0], *p1 = lds[1], *p2 = lds[2];

  stage(p0);                                   // tiles 0,1 in flight (8 loads)
  stage(p1);
  for (int t = 0; t < KT - 2; ++t) {
    stage(p2);                                 // tile t+2 -> 12 outstanding
    __builtin_amdgcn_sched_barrier(0);
    asm volatile("s_waitcnt vmcnt(8)" ::: "memory");   // tile t landed, never 0
    __builtin_amdgcn_sched_barrier(0);
    __builtin_amdgcn_s_barrier();              // all waves' tile-t chunks in LDS
    compute(p0);
    __builtin_amdgcn_sched_barrier(0);
    __builtin_amdgcn_s_barrier();              // all waves done reading p0
    unsigned short* ts = p0; p0 = p1; p1 = p2; p2 = ts;
  }
  // t = KT-2: 8 outstanding -> wait 4
  asm volatile("s_waitcnt vmcnt(4)" ::: "memory");
  __builtin_amdgcn_sched_barrier(0);
  __builtin_amdgcn_s_barrier();
  compute(p0);
  __builtin_amdgcn_sched_barrier(0);
  __builtin_amdgcn_s_barrier();
  // t = KT-1: 4 outstanding -> wait 0
  asm volatile("s_waitcnt vmcnt(0)" ::: "memory");
  __builtin_amdgcn_sched_barrier(0);
  __builtin_amdgcn_s_barrier();
  compute(p1);

  // ---- epilogue (branch-free GELU; full-tile fast path) ----
  const int rem = cnt - mt * 128;
  const int q4 = (lane >> 4) * 4;
  const int c15 = lane & 15;

  if (rem >= 128) {                            // wave-uniform: common path
    #pragma unroll
    for (int n = 0; n < 4; ++n) {
      const int col = nt * 128 + wn * 64 + n * 16 + c15;
      const float bv = bias[e * NCOL + col];
      #pragma unroll
      for (int m = 0; m < 4; ++m) {
        #pragma unroll
        for (int rr = 0; rr < 4; ++rr) {
          const int rloc = wm * 64 + m * 16 + q4 + rr;
          float v = acc[m][n][rr] + bv;
          if constexpr (PHASE == 1) v = gelu_f(v);
          Cout[(size_t)(base + mt * 128 + rloc) * NCOL + col] = __float2bfloat16(v);
        }
      }
    }
  } else {
    #pragma unroll
    for (int n = 0; n < 4; ++n) {
      const int col = nt * 128 + wn * 64 + n * 16 + c15;
      const float bv = bias[e * NCOL + col];
      #pragma unroll
      for (int m = 0; m < 4; ++m) {
        #pragma unroll
        for (int rr = 0; rr < 4; ++rr) {
          const int rloc = wm * 64 + m * 16 + q4 + rr;
          if (rloc < rem) {
            float v = acc[m][n][rr] + bv;
            if constexpr (PHASE == 1) v = gelu_f(v);
            Cout[(size_t)(base + mt * 128 + rloc) * NCOL + col] = __float2bfloat16(v);
          }
        }
      }
    }
  }
}

// ---------------- launch ----------------

extern "C" void kernel_launch(void* const* d_in, const int* in_sizes, int n_in,
                              void* d_out, int out_size, void* d_ws, size_t ws_size,
                              hipStream_t stream) {
  const float* x  = (const float*)d_in[0];
  const float* rw = (const float*)d_in[1];
  const float* rb = (const float*)d_in[2];
  const float* w1 = (const float*)d_in[3];
  const float* b1 = (const float*)d_in[4];
  const float* w2 = (const float*)d_in[5];
  const float* b2 = (const float*)d_in[6];
  float* out = (float*)d_out;

  char* p = (char*)d_ws;
  size_t used = 0;
  auto carve = [&](size_t bytes) {
    char* r = p + used;
    used += (bytes + 255) & ~(size_t)255;
    return (void*)r;
  };
  // xg (GEMM1 input) and ys (GEMM2 output) alias: xg dead once GEMM1 completes.
  __hip_bfloat16* xg  = (__hip_bfloat16*)carve((size_t)SLOT_CAP * D_DIM * 2);
  __hip_bfloat16* ys  = xg;
  __hip_bfloat16* w1t = (__hip_bfloat16*)carve((size_t)NEXP * F_DIM * D_DIM * 2);
  __hip_bfloat16* w2t = (__hip_bfloat16*)carve((size_t)NEXP * D_DIM * F_DIM * 2);
  __hip_bfloat16* h   = (__hip_bfloat16*)carve((size_t)SLOT_CAP * F_DIM * 2);
  int*   topk_idx   = (int*)carve((size_t)NTOK * 2 * 4);
  float* topk_w     = (float*)carve((size_t)NTOK * 2 * 4);
  int*   slot_token = (int*)carve((size_t)SLOT_CAP * 4);
  int*   slot_pos   = (int*)carve((size_t)NTOK * 2 * 4);
  int* counts  = (int*)carve(256);
  int* offsets = (int*)carve(256);
  int* cursors = (int*)carve(256);

  if (used > ws_size) {   // guard: deterministic zero output, diagnosable
    zero_out_kernel<<<8192, 256, 0, stream>>>(out);
    return;
  }

  init_counts_kernel<<<1, 64, 0, stream>>>(counts);
  router_kernel<<<NTOK / 4, 256, 0, stream>>>(x, rw, rb, topk_idx, topk_w, counts);
  offsets_kernel<<<1, 256, 0, stream>>>(counts, offsets, cursors, slot_token);
  scatter_kernel<<<NTOK / 256, 256, 0, stream>>>(topk_idx, cursors, slot_token, slot_pos);
  gather_x_kernel<<<SLOT_CAP, 256, 0, stream>>>(x, slot_token, xg);

  dim3 tb(16, 16);
  transpose_conv_kernel<<<dim3(F_DIM / 64, D_DIM / 64, NEXP), tb, 0, stream>>>(w1, w1t, D_DIM, F_DIM);
  transpose_conv_kernel<<<dim3(D_DIM / 64, F_DIM / 64, NEXP), tb, 0, stream>>>(w2, w2t, F_DIM, D_DIM);

  // grid: bid = slot*8 + e; GEMM1 slots = MT_MAX * NT1 = 64*32; GEMM2 = 64*8
  moe_gemm<1><<<NEXP * MT_MAX * (F_DIM / 128), 256, 0, stream>>>(
      xg, w1t, b1, counts, offsets, h);
  moe_gemm<2><<<NEXP * MT_MAX * (D_DIM / 128), 256, 0, stream>>>(
      h, w2t, b2, counts, offsets, ys);

  combine_kernel<<<NTOK, 256, 0, stream>>>(ys, slot_pos, topk_w, out);
}

// Round 9
// 986.246 us; speedup vs baseline: 1.0089x; 1.0089x over previous
//
#include <hip/hip_runtime.h>
#include <hip/hip_bf16.h>

typedef __attribute__((ext_vector_type(8))) __bf16 bf16x8;
typedef __attribute__((ext_vector_type(4))) float f32x4;

#define NTOK 8192
#define D_DIM 1024
#define F_DIM 4096
#define NEXP 8
#define SLOT_TOT 16384          // 2 * NTOK
#define SLOT_CAP 16640          // SLOT_TOT + 256 padding (tile overrun)
#define TILE_MAX 136            // sum ceil(cnt_e/128) <= 128 + 8

__device__ __forceinline__ unsigned short f2b(float f) {
  __hip_bfloat16 b = __float2bfloat16(f);
  return reinterpret_cast<unsigned short&>(b);
}

// tanh-form GELU (branch-free): max |err| vs exact erf-GELU ~3e-4.
__device__ __forceinline__ float gelu_f(float v) {
  const float y2 = v * (1.5957691216f + 0.0713548162f * v * v);
  return v * __builtin_amdgcn_rcpf(1.f + __expf(-y2));
}

__device__ __forceinline__ void gload_lds16(const void* g, void* l) {
  __builtin_amdgcn_global_load_lds(
      (__attribute__((address_space(1))) void*)g,
      (__attribute__((address_space(3))) void*)l, 16, 0, 0);
}

// ---------------- small kernels ----------------

__global__ void init_counts_kernel(int* counts) {
  if (threadIdx.x < NEXP) counts[threadIdx.x] = 0;
}

__global__ void zero_out_kernel(float* out) {
  const int i = blockIdx.x * 256 + threadIdx.x;
  reinterpret_cast<float4*>(out)[i] = make_float4(0.f, 0.f, 0.f, 0.f);
}

// fused scatter + gather: one block per token. Lanes 0/1 claim slots for the
// token's two experts; all 256 threads then copy the x row (f32->bf16) into
// both slot rows. slot order within an expert is nondeterministic but results
// are slot-position-independent (combine reads back via slot_pos).
__global__ void scatter_gather_kernel(const float* __restrict__ x,
                                      const int* __restrict__ topk_idx,
                                      int* __restrict__ cursors,
                                      int* __restrict__ slot_pos,
                                      __hip_bfloat16* __restrict__ xg) {
  __shared__ int ps[2];
  const int tok = blockIdx.x;
  const int tid = threadIdx.x;
  if (tid < 2) {
    const int e = topk_idx[tok * 2 + tid];
    const int p = atomicAdd(&cursors[e], 1);
    slot_pos[tok * 2 + tid] = p;
    ps[tid] = p;
  }
  __syncthreads();
  const int d = tid * 4;
  const float4 v = *reinterpret_cast<const float4*>(x + (size_t)tok * D_DIM + d);
  union { unsigned short u[4]; uint2 q; } o;
  o.u[0] = f2b(v.x); o.u[1] = f2b(v.y); o.u[2] = f2b(v.z); o.u[3] = f2b(v.w);
  *reinterpret_cast<uint2*>(xg + (size_t)ps[0] * D_DIM + d) = o.q;
  *reinterpret_cast<uint2*>(xg + (size_t)ps[1] * D_DIM + d) = o.q;
}

// out[tok] = w0 * ys[s0] + w1 * ys[s1]   (bias already inside ys)
__global__ void combine_kernel(const __hip_bfloat16* __restrict__ ys,
                               const int* __restrict__ slot_pos,
                               const float* __restrict__ topk_w,
                               float* __restrict__ out) {
  const int tok = blockIdx.x;
  const int d = threadIdx.x * 4;
  const int s0 = slot_pos[tok * 2], s1 = slot_pos[tok * 2 + 1];
  const float w0 = topk_w[tok * 2], w1 = topk_w[tok * 2 + 1];
  union { unsigned short u[4]; uint2 q; } a, b;
  a.q = *reinterpret_cast<const uint2*>(ys + (size_t)s0 * D_DIM + d);
  b.q = *reinterpret_cast<const uint2*>(ys + (size_t)s1 * D_DIM + d);
  float4 rr;
  float va[4];
  #pragma unroll
  for (int i = 0; i < 4; ++i) {
    unsigned int ua = (unsigned int)a.u[i] << 16;
    unsigned int ub = (unsigned int)b.u[i] << 16;
    va[i] = w0 * reinterpret_cast<float&>(ua) + w1 * reinterpret_cast<float&>(ub);
  }
  rr.x = va[0]; rr.y = va[1]; rr.z = va[2]; rr.w = va[3];
  *reinterpret_cast<float4*>(out + (size_t)tok * D_DIM + d) = rr;
}

// src: per-expert [R][C] f32  ->  dst: per-expert [C][R] bf16
__global__ void transpose_conv_kernel(const float* __restrict__ src,
                                      __hip_bfloat16* __restrict__ dst,
                                      int R, int C) {
  __shared__ float tile[64][65];
  const int e = blockIdx.z;
  src += (size_t)e * R * C;
  dst += (size_t)e * R * C;
  const int c0 = blockIdx.x * 64, r0 = blockIdx.y * 64;
  const int tx = threadIdx.x, ty = threadIdx.y;   // (16, 16)
  #pragma unroll
  for (int j = 0; j < 4; ++j) {
    const float4 v = *reinterpret_cast<const float4*>(
        &src[(size_t)(r0 + ty + j * 16) * C + c0 + tx * 4]);
    tile[ty + j * 16][tx * 4 + 0] = v.x;
    tile[ty + j * 16][tx * 4 + 1] = v.y;
    tile[ty + j * 16][tx * 4 + 2] = v.z;
    tile[ty + j * 16][tx * 4 + 3] = v.w;
  }
  __syncthreads();
  #pragma unroll
  for (int j = 0; j < 4; ++j) {
    const int c = ty + j * 16;
    union { unsigned short u[4]; uint2 d; } o;
    #pragma unroll
    for (int i = 0; i < 4; ++i) o.u[i] = f2b(tile[tx * 4 + i][c]);
    *reinterpret_cast<uint2*>(&dst[(size_t)(c0 + c) * R + r0 + tx * 4]) = o.d;
  }
}

// ---------------- router ----------------
__global__ void router_kernel(const float* __restrict__ x,
                              const float* __restrict__ rw,
                              const float* __restrict__ rb,
                              int* __restrict__ topk_idx,
                              float* __restrict__ topk_w,
                              int* __restrict__ counts) {
  __shared__ float rwT[NEXP * D_DIM];   // transposed [e][d], 32 KB
  const int tid = threadIdx.x;
  for (int i = tid; i < NEXP * D_DIM; i += 256) {
    const int d = i >> 3, e = i & 7;
    rwT[e * D_DIM + d] = rw[i];
  }
  __syncthreads();

  const int wave = tid >> 6, lane = tid & 63;
  const int tok = blockIdx.x * 4 + wave;
  const float* xr = x + (size_t)tok * D_DIM;

  float acc[NEXP];
  #pragma unroll
  for (int e = 0; e < NEXP; ++e) acc[e] = 0.f;

  for (int i = 0; i < D_DIM / 64; ++i) {
    const int d = i * 64 + lane;
    const float xv = xr[d];
    #pragma unroll
    for (int e = 0; e < NEXP; ++e) acc[e] += xv * rwT[e * D_DIM + d];
  }
  #pragma unroll
  for (int off = 32; off > 0; off >>= 1) {
    #pragma unroll
    for (int e = 0; e < NEXP; ++e) acc[e] += __shfl_xor(acc[e], off);
  }

  if (lane == 0) {
    float l[NEXP];
    #pragma unroll
    for (int e = 0; e < NEXP; ++e) l[e] = acc[e] + rb[e];
    int i1 = 0;
    #pragma unroll
    for (int e = 1; e < NEXP; ++e) if (l[e] > l[i1]) i1 = e;
    int i2 = (i1 == 0) ? 1 : 0;
    #pragma unroll
    for (int e = 0; e < NEXP; ++e) if (e != i1 && e != i2 && l[e] > l[i2]) i2 = e;
    const float w1 = 1.f / (1.f + __expf(l[i2] - l[i1]));
    topk_idx[tok * 2 + 0] = i1;
    topk_idx[tok * 2 + 1] = i2;
    topk_w[tok * 2 + 0] = w1;
    topk_w[tok * 2 + 1] = 1.f - w1;
    atomicAdd(&counts[i1], 1);
    atomicAdd(&counts[i2], 1);
  }
}

// builds offsets, cursors, and the compact (expert, mt) tile table
__global__ void offsets_kernel(const int* __restrict__ counts,
                               int* __restrict__ offsets,
                               int* __restrict__ cursors,
                               int* __restrict__ tile_meta) {
  if (threadIdx.x == 0) {
    int s = 0;
    for (int e = 0; e < NEXP; ++e) { offsets[e] = s; cursors[e] = s; s += counts[e]; }
    offsets[NEXP] = s;
    int n = 0;
    for (int e = 0; e < NEXP; ++e) {
      const int ntile = (counts[e] + 127) >> 7;
      for (int m = 0; m < ntile && n < TILE_MAX; ++m) tile_meta[n++] = e | (m << 8);
    }
    for (; n < TILE_MAX; ++n) tile_meta[n] = 0 | (1 << 22);   // mt huge -> exits
  }
}

// ---------------- MFMA GEMMs: exact T3-minimum 2-phase recipe ----------------
// 128x128 tile, BK=32, 4 waves (2Mx2N, wave tile 64x64, acc[4][4]).
// Double-buffered 2x16KB LDS. Per K-step:
//   stage(next buf)     <- 4 global_load_lds issued, NO fence after
//   compute(cur buf)    <- compiler interleaves ds_read/MFMA/gload freely,
//                          auto fine-grained lgkmcnt (m97 behavior)
//   __syncthreads()     <- ONE barrier: drains own vmcnt (next tile resident
//                          for this wave) + syncs (cur buf free for overwrite)
// No sched_barrier / manual vmcnt / setprio: m141 & m190 show these hurt the
// lockstep 2-phase structure; the recipe (m228d/m230) measures 622-682 TF.
// Compact tile grid: bid/NT -> tile_meta (expert,mt), bid%NT -> nt fastest
// (consecutive blocks share the 256KB A panel; B reused via L2/L3).
template <int PHASE>
__global__ __launch_bounds__(256, 4) void moe_gemm(
    const __hip_bfloat16* __restrict__ A,   // [SLOT_CAP][K] slot-ordered
    const __hip_bfloat16* __restrict__ B,   // [NEXP][NCOL][K]
    const float* __restrict__ bias,         // [NEXP][NCOL]
    const int* __restrict__ counts,
    const int* __restrict__ offsets,
    const int* __restrict__ tile_meta,
    __hip_bfloat16* __restrict__ Cout) {    // [SLOT_CAP][NCOL]
  constexpr int K    = (PHASE == 1) ? D_DIM : F_DIM;
  constexpr int NCOL = (PHASE == 1) ? F_DIM : D_DIM;
  constexpr int NT   = NCOL / 128;
  constexpr int KT   = K / 32;

  const int bid = blockIdx.x;
  const int j = bid / NT, nt = bid % NT;
  const int meta = tile_meta[j];
  const int e = meta & 255, mt = meta >> 8;
  const int cnt = counts[e];
  if (mt * 128 >= cnt) return;
  const int base = offsets[e];

  __shared__ unsigned short lds[2][8192];   // per buf: A [0,4096) | B [4096,8192)

  const int tid = threadIdx.x;
  const int w = tid >> 6, lane = tid & 63;
  const int r = lane & 15, kg = lane >> 4;
  const int wm = w >> 1, wn = w & 1;

  // wave w stages A chunks {w, w+4} and B chunks {w, w+4}; chunk c (1KB) holds
  // rows c*16+(lane&15), k=(lane>>4)*8..+8 at lane*16B (gload-linear,
  // ds_read_b128 conflict-free — measured 0 conflicts).
  const __hip_bfloat16* gA0 = A + (size_t)(base + mt * 128 + w * 16 + r) * K + kg * 8;
  const __hip_bfloat16* gA1 = gA0 + (size_t)64 * K;
  const __hip_bfloat16* gB0 = B + ((size_t)e * NCOL + nt * 128 + w * 16 + r) * K + kg * 8;
  const __hip_bfloat16* gB1 = gB0 + (size_t)64 * K;

  f32x4 acc[4][4] = {};

  auto stage = [&](unsigned short* buf) {
    gload_lds16(gA0, buf + w * 512);
    gload_lds16(gA1, buf + (w + 4) * 512);
    gload_lds16(gB0, buf + 4096 + w * 512);
    gload_lds16(gB1, buf + 4096 + (w + 4) * 512);
    gA0 += 32; gA1 += 32; gB0 += 32; gB1 += 32;
  };
  auto compute = [&](const unsigned short* buf) {
    bf16x8 af[4], bfr[4];
    #pragma unroll
    for (int i2 = 0; i2 < 4; ++i2) {
      af[i2]  = *(const bf16x8*)(buf + (wm * 4 + i2) * 512 + lane * 8);
      bfr[i2] = *(const bf16x8*)(buf + 4096 + (wn * 4 + i2) * 512 + lane * 8);
    }
    #pragma unroll
    for (int mi = 0; mi < 4; ++mi)
      #pragma unroll
      for (int ni = 0; ni < 4; ++ni)
        acc[mi][ni] = __builtin_amdgcn_mfma_f32_16x16x32_bf16(
            af[mi], bfr[ni], acc[mi][ni], 0, 0, 0);
  };

  unsigned short* pc = lds[0];
  unsigned short* pn = lds[1];

  stage(pc);
  __syncthreads();                       // prologue: tile 0 resident
  for (int t = 0; t < KT - 1; ++t) {
    stage(pn);                           // issue next tile (overlaps compute)
    compute(pc);                         // ds_read + 16 MFMA, free interleave
    __syncthreads();                     // one barrier: pn resident, pc free
    unsigned short* ts = pc; pc = pn; pn = ts;
  }
  compute(pc);                           // last tile

  // ---- epilogue (branch-free GELU; full-tile fast path) ----
  const int rem = cnt - mt * 128;
  const int q4 = (lane >> 4) * 4;
  const int c15 = lane & 15;

  if (rem >= 128) {                      // wave-uniform common path
    #pragma unroll
    for (int n = 0; n < 4; ++n) {
      const int col = nt * 128 + wn * 64 + n * 16 + c15;
      const float bv = bias[e * NCOL + col];
      #pragma unroll
      for (int m = 0; m < 4; ++m) {
        #pragma unroll
        for (int rr = 0; rr < 4; ++rr) {
          const int rloc = wm * 64 + m * 16 + q4 + rr;
          float v = acc[m][n][rr] + bv;
          if constexpr (PHASE == 1) v = gelu_f(v);
          Cout[(size_t)(base + mt * 128 + rloc) * NCOL + col] = __float2bfloat16(v);
        }
      }
    }
  } else {
    #pragma unroll
    for (int n = 0; n < 4; ++n) {
      const int col = nt * 128 + wn * 64 + n * 16 + c15;
      const float bv = bias[e * NCOL + col];
      #pragma unroll
      for (int m = 0; m < 4; ++m) {
        #pragma unroll
        for (int rr = 0; rr < 4; ++rr) {
          const int rloc = wm * 64 + m * 16 + q4 + rr;
          if (rloc < rem) {
            float v = acc[m][n][rr] + bv;
            if constexpr (PHASE == 1) v = gelu_f(v);
            Cout[(size_t)(base + mt * 128 + rloc) * NCOL + col] = __float2bfloat16(v);
          }
        }
      }
    }
  }
}

// ---------------- launch ----------------

extern "C" void kernel_launch(void* const* d_in, const int* in_sizes, int n_in,
                              void* d_out, int out_size, void* d_ws, size_t ws_size,
                              hipStream_t stream) {
  const float* x  = (const float*)d_in[0];
  const float* rw = (const float*)d_in[1];
  const float* rb = (const float*)d_in[2];
  const float* w1 = (const float*)d_in[3];
  const float* b1 = (const float*)d_in[4];
  const float* w2 = (const float*)d_in[5];
  const float* b2 = (const float*)d_in[6];
  float* out = (float*)d_out;

  char* p = (char*)d_ws;
  size_t used = 0;
  auto carve = [&](size_t bytes) {
    char* r = p + used;
    used += (bytes + 255) & ~(size_t)255;
    return (void*)r;
  };
  // xg (GEMM1 input) and ys (GEMM2 output) alias: xg dead once GEMM1 completes.
  __hip_bfloat16* xg  = (__hip_bfloat16*)carve((size_t)SLOT_CAP * D_DIM * 2);
  __hip_bfloat16* ys  = xg;
  __hip_bfloat16* w1t = (__hip_bfloat16*)carve((size_t)NEXP * F_DIM * D_DIM * 2);
  __hip_bfloat16* w2t = (__hip_bfloat16*)carve((size_t)NEXP * D_DIM * F_DIM * 2);
  __hip_bfloat16* h   = (__hip_bfloat16*)carve((size_t)SLOT_CAP * F_DIM * 2);
  int*   topk_idx   = (int*)carve((size_t)NTOK * 2 * 4);
  float* topk_w     = (float*)carve((size_t)NTOK * 2 * 4);
  int*   slot_pos   = (int*)carve((size_t)NTOK * 2 * 4);
  int*   tile_meta  = (int*)carve(TILE_MAX * 4);
  int* counts  = (int*)carve(256);
  int* offsets = (int*)carve(256);
  int* cursors = (int*)carve(256);

  if (used > ws_size) {   // guard: deterministic zero output, diagnosable
    zero_out_kernel<<<8192, 256, 0, stream>>>(out);
    return;
  }

  init_counts_kernel<<<1, 64, 0, stream>>>(counts);
  router_kernel<<<NTOK / 4, 256, 0, stream>>>(x, rw, rb, topk_idx, topk_w, counts);
  offsets_kernel<<<1, 64, 0, stream>>>(counts, offsets, cursors, tile_meta);
  scatter_gather_kernel<<<NTOK, 256, 0, stream>>>(x, topk_idx, cursors, slot_pos, xg);

  dim3 tb(16, 16);
  transpose_conv_kernel<<<dim3(F_DIM / 64, D_DIM / 64, NEXP), tb, 0, stream>>>(w1, w1t, D_DIM, F_DIM);
  transpose_conv_kernel<<<dim3(D_DIM / 64, F_DIM / 64, NEXP), tb, 0, stream>>>(w2, w2t, F_DIM, D_DIM);

  moe_gemm<1><<<TILE_MAX * (F_DIM / 128), 256, 0, stream>>>(
      xg, w1t, b1, counts, offsets, tile_meta, h);
  moe_gemm<2><<<TILE_MAX * (D_DIM / 128), 256, 0, stream>>>(
      h, w2t, b2, counts, offsets, tile_meta, ys);

  combine_kernel<<<NTOK, 256, 0, stream>>>(ys, slot_pos, topk_w, out);
}

// Round 10
// 961.720 us; speedup vs baseline: 1.0346x; 1.0255x over previous
//
#include <hip/hip_runtime.h>
#include <hip/hip_bf16.h>

typedef __attribute__((ext_vector_type(8))) __bf16 bf16x8;
typedef __attribute__((ext_vector_type(4))) float f32x4;

#define NTOK 8192
#define D_DIM 1024
#define F_DIM 4096
#define NEXP 8
#define SLOT_TOT 16384          // 2 * NTOK
#define SLOT_CAP 16640          // SLOT_TOT + 256 padding (256-tile overrun)
#define TILE_MAX 136            // sum ceil(cnt_e/128) <= 128 + 8
#define TILE_MAX2 72            // sum ceil(cnt_e/256) <= 64 + 8

__device__ __forceinline__ unsigned short f2b(float f) {
  __hip_bfloat16 b = __float2bfloat16(f);
  return reinterpret_cast<unsigned short&>(b);
}

// tanh-form GELU (branch-free): max |err| vs exact erf-GELU ~3e-4.
__device__ __forceinline__ float gelu_f(float v) {
  const float y2 = v * (1.5957691216f + 0.0713548162f * v * v);
  return v * __builtin_amdgcn_rcpf(1.f + __expf(-y2));
}

__device__ __forceinline__ void gload_lds16(const void* g, void* l) {
  __builtin_amdgcn_global_load_lds(
      (__attribute__((address_space(1))) void*)g,
      (__attribute__((address_space(3))) void*)l, 16, 0, 0);
}

// ---------------- small kernels ----------------

__global__ void init_counts_kernel(int* counts) {
  if (threadIdx.x < NEXP) counts[threadIdx.x] = 0;
}

__global__ void zero_out_kernel(float* out) {
  const int i = blockIdx.x * 256 + threadIdx.x;
  reinterpret_cast<float4*>(out)[i] = make_float4(0.f, 0.f, 0.f, 0.f);
}

// fused scatter + gather: one block per token.
__global__ void scatter_gather_kernel(const float* __restrict__ x,
                                      const int* __restrict__ topk_idx,
                                      int* __restrict__ cursors,
                                      int* __restrict__ slot_pos,
                                      __hip_bfloat16* __restrict__ xg) {
  __shared__ int ps[2];
  const int tok = blockIdx.x;
  const int tid = threadIdx.x;
  if (tid < 2) {
    const int e = topk_idx[tok * 2 + tid];
    const int p = atomicAdd(&cursors[e], 1);
    slot_pos[tok * 2 + tid] = p;
    ps[tid] = p;
  }
  __syncthreads();
  const int d = tid * 4;
  const float4 v = *reinterpret_cast<const float4*>(x + (size_t)tok * D_DIM + d);
  union { unsigned short u[4]; uint2 q; } o;
  o.u[0] = f2b(v.x); o.u[1] = f2b(v.y); o.u[2] = f2b(v.z); o.u[3] = f2b(v.w);
  *reinterpret_cast<uint2*>(xg + (size_t)ps[0] * D_DIM + d) = o.q;
  *reinterpret_cast<uint2*>(xg + (size_t)ps[1] * D_DIM + d) = o.q;
}

// out[tok] = w0 * ys[s0] + w1 * ys[s1]   (bias already inside ys)
__global__ void combine_kernel(const __hip_bfloat16* __restrict__ ys,
                               const int* __restrict__ slot_pos,
                               const float* __restrict__ topk_w,
                               float* __restrict__ out) {
  const int tok = blockIdx.x;
  const int d = threadIdx.x * 4;
  const int s0 = slot_pos[tok * 2], s1 = slot_pos[tok * 2 + 1];
  const float w0 = topk_w[tok * 2], w1 = topk_w[tok * 2 + 1];
  union { unsigned short u[4]; uint2 q; } a, b;
  a.q = *reinterpret_cast<const uint2*>(ys + (size_t)s0 * D_DIM + d);
  b.q = *reinterpret_cast<const uint2*>(ys + (size_t)s1 * D_DIM + d);
  float4 rr;
  float va[4];
  #pragma unroll
  for (int i = 0; i < 4; ++i) {
    unsigned int ua = (unsigned int)a.u[i] << 16;
    unsigned int ub = (unsigned int)b.u[i] << 16;
    va[i] = w0 * reinterpret_cast<float&>(ua) + w1 * reinterpret_cast<float&>(ub);
  }
  rr.x = va[0]; rr.y = va[1]; rr.z = va[2]; rr.w = va[3];
  *reinterpret_cast<float4*>(out + (size_t)tok * D_DIM + d) = rr;
}

// src: per-expert [R][C] f32 -> dst: per-expert [C][R] bf16. 64x64 tile,
// 256 threads; float4 loads, uint4 (8x bf16, 16 B) stores.
__global__ void transpose_conv_kernel(const float* __restrict__ src,
                                      __hip_bfloat16* __restrict__ dst,
                                      int R, int C) {
  __shared__ float tile[64][65];
  const int e = blockIdx.z;
  src += (size_t)e * R * C;
  dst += (size_t)e * R * C;
  const int c0 = blockIdx.x * 64, r0 = blockIdx.y * 64;
  const int tid = threadIdx.x;
  const int lr = tid >> 4, lc4 = (tid & 15) * 4;
  #pragma unroll
  for (int pass = 0; pass < 4; ++pass) {
    const int rr = pass * 16 + lr;
    const float4 v = *reinterpret_cast<const float4*>(
        &src[(size_t)(r0 + rr) * C + c0 + lc4]);
    tile[rr][lc4 + 0] = v.x; tile[rr][lc4 + 1] = v.y;
    tile[rr][lc4 + 2] = v.z; tile[rr][lc4 + 3] = v.w;
  }
  __syncthreads();
  const int sc = tid >> 3, sr8 = (tid & 7) * 8;
  #pragma unroll
  for (int pass = 0; pass < 2; ++pass) {
    const int c = pass * 32 + sc;
    union { unsigned short u[8]; uint4 q; } o;
    #pragma unroll
    for (int i = 0; i < 8; ++i) o.u[i] = f2b(tile[sr8 + i][c]);
    *reinterpret_cast<uint4*>(&dst[(size_t)(c0 + c) * R + r0 + sr8]) = o.q;
  }
}

// ---------------- router ----------------
__global__ void router_kernel(const float* __restrict__ x,
                              const float* __restrict__ rw,
                              const float* __restrict__ rb,
                              int* __restrict__ topk_idx,
                              float* __restrict__ topk_w,
                              int* __restrict__ counts) {
  __shared__ float rwT[NEXP * D_DIM];   // transposed [e][d], 32 KB
  const int tid = threadIdx.x;
  for (int i = tid; i < NEXP * D_DIM; i += 256) {
    const int d = i >> 3, e = i & 7;
    rwT[e * D_DIM + d] = rw[i];
  }
  __syncthreads();

  const int wave = tid >> 6, lane = tid & 63;
  const int tok = blockIdx.x * 4 + wave;
  const float* xr = x + (size_t)tok * D_DIM;

  float acc[NEXP];
  #pragma unroll
  for (int e = 0; e < NEXP; ++e) acc[e] = 0.f;

  for (int i = 0; i < D_DIM / 64; ++i) {
    const int d = i * 64 + lane;
    const float xv = xr[d];
    #pragma unroll
    for (int e = 0; e < NEXP; ++e) acc[e] += xv * rwT[e * D_DIM + d];
  }
  #pragma unroll
  for (int off = 32; off > 0; off >>= 1) {
    #pragma unroll
    for (int e = 0; e < NEXP; ++e) acc[e] += __shfl_xor(acc[e], off);
  }

  if (lane == 0) {
    float l[NEXP];
    #pragma unroll
    for (int e = 0; e < NEXP; ++e) l[e] = acc[e] + rb[e];
    int i1 = 0;
    #pragma unroll
    for (int e = 1; e < NEXP; ++e) if (l[e] > l[i1]) i1 = e;
    int i2 = (i1 == 0) ? 1 : 0;
    #pragma unroll
    for (int e = 0; e < NEXP; ++e) if (e != i1 && e != i2 && l[e] > l[i2]) i2 = e;
    const float w1 = 1.f / (1.f + __expf(l[i2] - l[i1]));
    topk_idx[tok * 2 + 0] = i1;
    topk_idx[tok * 2 + 1] = i2;
    topk_w[tok * 2 + 0] = w1;
    topk_w[tok * 2 + 1] = 1.f - w1;
    atomicAdd(&counts[i1], 1);
    atomicAdd(&counts[i2], 1);
  }
}

// builds offsets, cursors, and compact tile tables for BM=128 and BM=256
__global__ void offsets_kernel(const int* __restrict__ counts,
                               int* __restrict__ offsets,
                               int* __restrict__ cursors,
                               int* __restrict__ tile_meta,     // 128-stride
                               int* __restrict__ tile_meta2) {  // 256-stride
  if (threadIdx.x == 0) {
    int s = 0;
    for (int e = 0; e < NEXP; ++e) { offsets[e] = s; cursors[e] = s; s += counts[e]; }
    offsets[NEXP] = s;
    int n = 0;
    for (int e = 0; e < NEXP; ++e) {
      const int nt = (counts[e] + 127) >> 7;
      for (int m = 0; m < nt && n < TILE_MAX; ++m) tile_meta[n++] = e | (m << 8);
    }
    for (; n < TILE_MAX; ++n) tile_meta[n] = 0 | (1 << 22);
    n = 0;
    for (int e = 0; e < NEXP; ++e) {
      const int nt = (counts[e] + 255) >> 8;
      for (int m = 0; m < nt && n < TILE_MAX2; ++m) tile_meta2[n++] = e | (m << 8);
    }
    for (; n < TILE_MAX2; ++n) tile_meta2[n] = 0 | (1 << 22);
  }
}

// ------- GEMM1: 256x256, BK=64, 512 thr, 2-phase T3-minimum (m230 regime) -------
// 8 waves (2M x 4N), wave tile 128x64, acc[8][4] (128 f32 -> AGPR-backed).
// LDS: 2 bufs x 64 KB (A 32 KB = 32 chunks of 16rows x 32k, B same) = 128 KB
// -> 1 block/CU, 8 waves, 2 waves/SIMD (reg cap 256). Schedule per K-step:
//   stage(next)  <- 8 gload_lds, no fence
//   compute(cur) <- 24 ds_read_b128 + 64 MFMA, free compiler interleave
//   __syncthreads() <- one barrier (drains vmcnt under ~600+ cyc of compute)
// AI = 128 FLOP/B: staged bytes halve vs 128^2 -> staging-roofline ~2x.
__global__ __launch_bounds__(512, 2) void moe_gemm1(
    const __hip_bfloat16* __restrict__ A,   // [SLOT_CAP][1024] slot-ordered
    const __hip_bfloat16* __restrict__ B,   // [NEXP][4096][1024]
    const float* __restrict__ bias,         // [NEXP][4096]
    const int* __restrict__ counts,
    const int* __restrict__ offsets,
    const int* __restrict__ tile_meta2,
    __hip_bfloat16* __restrict__ Hout) {    // [SLOT_CAP][4096]
  constexpr int K = D_DIM, NCOL = F_DIM;
  constexpr int KT = K / 64;

  const int bid = blockIdx.x;
  const int j = bid >> 4, nt = bid & 15;
  const int meta = tile_meta2[j];
  const int e = meta & 255, mt = meta >> 8;
  const int cnt = counts[e];
  if (mt * 256 >= cnt) return;
  const int base = offsets[e];

  __shared__ unsigned short lds[2][32768];  // per buf: A [0,16384) | B [16384,32768)

  const int tid = threadIdx.x;
  const int w = tid >> 6, lane = tid & 63;
  const int r = lane & 15, kg = lane >> 4;
  const int wm = w >> 2, wn = w & 3;        // 2M x 4N

  // chunk c (1 KB) = 16 rows x 32 k; A chunk index = kk*16 + rowgroup.
  // wave w stages A rowgroups {w, w+8} x kk {0,1}, B colgroups same.
  const __hip_bfloat16* gA0 = A + (size_t)(base + mt * 256 + w * 16 + r) * K + kg * 8;
  const __hip_bfloat16* gA1 = gA0 + (size_t)128 * K;
  const __hip_bfloat16* gB0 = B + ((size_t)e * NCOL + nt * 256 + w * 16 + r) * K + kg * 8;
  const __hip_bfloat16* gB1 = gB0 + (size_t)128 * K;

  f32x4 acc[8][4] = {};

  auto stage = [&](unsigned short* buf) {
    gload_lds16(gA0,      buf + w * 512);
    gload_lds16(gA1,      buf + (w + 8) * 512);
    gload_lds16(gA0 + 32, buf + (16 + w) * 512);
    gload_lds16(gA1 + 32, buf + (16 + w + 8) * 512);
    gload_lds16(gB0,      buf + 16384 + w * 512);
    gload_lds16(gB1,      buf + 16384 + (w + 8) * 512);
    gload_lds16(gB0 + 32, buf + 16384 + (16 + w) * 512);
    gload_lds16(gB1 + 32, buf + 16384 + (16 + w + 8) * 512);
    gA0 += 64; gA1 += 64; gB0 += 64; gB1 += 64;
  };
  auto compute = [&](const unsigned short* buf) {
    #pragma unroll
    for (int kk = 0; kk < 2; ++kk) {
      bf16x8 af[8], bfr[4];
      #pragma unroll
      for (int m = 0; m < 8; ++m)
        af[m] = *(const bf16x8*)(buf + (kk * 16 + wm * 8 + m) * 512 + lane * 8);
      #pragma unroll
      for (int n = 0; n < 4; ++n)
        bfr[n] = *(const bf16x8*)(buf + 16384 + (kk * 16 + wn * 4 + n) * 512 + lane * 8);
      #pragma unroll
      for (int m = 0; m < 8; ++m)
        #pragma unroll
        for (int n = 0; n < 4; ++n)
          acc[m][n] = __builtin_amdgcn_mfma_f32_16x16x32_bf16(
              af[m], bfr[n], acc[m][n], 0, 0, 0);
    }
  };

  unsigned short* pc = lds[0];
  unsigned short* pn = lds[1];

  stage(pc);
  __syncthreads();
  for (int t = 0; t < KT - 1; ++t) {
    stage(pn);
    compute(pc);
    __syncthreads();
    unsigned short* ts = pc; pc = pn; pn = ts;
  }
  compute(pc);

  // epilogue: gelu(acc + b1) -> h
  const int rem = cnt - mt * 256;
  const int q4 = (lane >> 4) * 4;
  const int c15 = lane & 15;

  if (rem >= 256) {
    #pragma unroll
    for (int n = 0; n < 4; ++n) {
      const int col = nt * 256 + wn * 64 + n * 16 + c15;
      const float bv = bias[e * NCOL + col];
      #pragma unroll
      for (int m = 0; m < 8; ++m)
        #pragma unroll
        for (int rr = 0; rr < 4; ++rr) {
          const int rloc = wm * 128 + m * 16 + q4 + rr;
          Hout[(size_t)(base + mt * 256 + rloc) * NCOL + col] =
              __float2bfloat16(gelu_f(acc[m][n][rr] + bv));
        }
    }
  } else {
    #pragma unroll
    for (int n = 0; n < 4; ++n) {
      const int col = nt * 256 + wn * 64 + n * 16 + c15;
      const float bv = bias[e * NCOL + col];
      #pragma unroll
      for (int m = 0; m < 8; ++m)
        #pragma unroll
        for (int rr = 0; rr < 4; ++rr) {
          const int rloc = wm * 128 + m * 16 + q4 + rr;
          if (rloc < rem)
            Hout[(size_t)(base + mt * 256 + rloc) * NCOL + col] =
                __float2bfloat16(gelu_f(acc[m][n][rr] + bv));
        }
    }
  }
}

// ------- GEMM2: 128x128 T3-minimum (r9, proven) -------
__global__ __launch_bounds__(256, 4) void moe_gemm2(
    const __hip_bfloat16* __restrict__ A,   // h [SLOT_CAP][4096]
    const __hip_bfloat16* __restrict__ B,   // w2t [NEXP][1024][4096]
    const float* __restrict__ bias,         // [NEXP][1024]
    const int* __restrict__ counts,
    const int* __restrict__ offsets,
    const int* __restrict__ tile_meta,
    __hip_bfloat16* __restrict__ Cout) {    // ys [SLOT_CAP][1024]
  constexpr int K = F_DIM, NCOL = D_DIM;
  constexpr int NT = NCOL / 128;
  constexpr int KT = K / 32;

  const int bid = blockIdx.x;
  const int j = bid / NT, nt = bid % NT;
  const int meta = tile_meta[j];
  const int e = meta & 255, mt = meta >> 8;
  const int cnt = counts[e];
  if (mt * 128 >= cnt) return;
  const int base = offsets[e];

  __shared__ unsigned short lds[2][8192];

  const int tid = threadIdx.x;
  const int w = tid >> 6, lane = tid & 63;
  const int r = lane & 15, kg = lane >> 4;
  const int wm = w >> 1, wn = w & 1;

  const __hip_bfloat16* gA0 = A + (size_t)(base + mt * 128 + w * 16 + r) * K + kg * 8;
  const __hip_bfloat16* gA1 = gA0 + (size_t)64 * K;
  const __hip_bfloat16* gB0 = B + ((size_t)e * NCOL + nt * 128 + w * 16 + r) * K + kg * 8;
  const __hip_bfloat16* gB1 = gB0 + (size_t)64 * K;

  f32x4 acc[4][4] = {};

  auto stage = [&](unsigned short* buf) {
    gload_lds16(gA0, buf + w * 512);
    gload_lds16(gA1, buf + (w + 4) * 512);
    gload_lds16(gB0, buf + 4096 + w * 512);
    gload_lds16(gB1, buf + 4096 + (w + 4) * 512);
    gA0 += 32; gA1 += 32; gB0 += 32; gB1 += 32;
  };
  auto compute = [&](const unsigned short* buf) {
    bf16x8 af[4], bfr[4];
    #pragma unroll
    for (int i2 = 0; i2 < 4; ++i2) {
      af[i2]  = *(const bf16x8*)(buf + (wm * 4 + i2) * 512 + lane * 8);
      bfr[i2] = *(const bf16x8*)(buf + 4096 + (wn * 4 + i2) * 512 + lane * 8);
    }
    #pragma unroll
    for (int mi = 0; mi < 4; ++mi)
      #pragma unroll
      for (int ni = 0; ni < 4; ++ni)
        acc[mi][ni] = __builtin_amdgcn_mfma_f32_16x16x32_bf16(
            af[mi], bfr[ni], acc[mi][ni], 0, 0, 0);
  };

  unsigned short* pc = lds[0];
  unsigned short* pn = lds[1];

  stage(pc);
  __syncthreads();
  for (int t = 0; t < KT - 1; ++t) {
    stage(pn);
    compute(pc);
    __syncthreads();
    unsigned short* ts = pc; pc = pn; pn = ts;
  }
  compute(pc);

  const int rem = cnt - mt * 128;
  const int q4 = (lane >> 4) * 4;
  const int c15 = lane & 15;

  if (rem >= 128) {
    #pragma unroll
    for (int n = 0; n < 4; ++n) {
      const int col = nt * 128 + wn * 64 + n * 16 + c15;
      const float bv = bias[e * NCOL + col];
      #pragma unroll
      for (int m = 0; m < 4; ++m)
        #pragma unroll
        for (int rr = 0; rr < 4; ++rr) {
          const int rloc = wm * 64 + m * 16 + q4 + rr;
          Cout[(size_t)(base + mt * 128 + rloc) * NCOL + col] =
              __float2bfloat16(acc[m][n][rr] + bv);
        }
    }
  } else {
    #pragma unroll
    for (int n = 0; n < 4; ++n) {
      const int col = nt * 128 + wn * 64 + n * 16 + c15;
      const float bv = bias[e * NCOL + col];
      #pragma unroll
      for (int m = 0; m < 4; ++m)
        #pragma unroll
        for (int rr = 0; rr < 4; ++rr) {
          const int rloc = wm * 64 + m * 16 + q4 + rr;
          if (rloc < rem)
            Cout[(size_t)(base + mt * 128 + rloc) * NCOL + col] =
                __float2bfloat16(acc[m][n][rr] + bv);
        }
    }
  }
}

// ---------------- launch ----------------

extern "C" void kernel_launch(void* const* d_in, const int* in_sizes, int n_in,
                              void* d_out, int out_size, void* d_ws, size_t ws_size,
                              hipStream_t stream) {
  const float* x  = (const float*)d_in[0];
  const float* rw = (const float*)d_in[1];
  const float* rb = (const float*)d_in[2];
  const float* w1 = (const float*)d_in[3];
  const float* b1 = (const float*)d_in[4];
  const float* w2 = (const float*)d_in[5];
  const float* b2 = (const float*)d_in[6];
  float* out = (float*)d_out;

  char* p = (char*)d_ws;
  size_t used = 0;
  auto carve = [&](size_t bytes) {
    char* r = p + used;
    used += (bytes + 255) & ~(size_t)255;
    return (void*)r;
  };
  __hip_bfloat16* xg  = (__hip_bfloat16*)carve((size_t)SLOT_CAP * D_DIM * 2);
  __hip_bfloat16* ys  = xg;   // alias: xg dead after GEMM1
  __hip_bfloat16* w1t = (__hip_bfloat16*)carve((size_t)NEXP * F_DIM * D_DIM * 2);
  __hip_bfloat16* w2t = (__hip_bfloat16*)carve((size_t)NEXP * D_DIM * F_DIM * 2);
  __hip_bfloat16* h   = (__hip_bfloat16*)carve((size_t)SLOT_CAP * F_DIM * 2);
  int*   topk_idx   = (int*)carve((size_t)NTOK * 2 * 4);
  float* topk_w     = (float*)carve((size_t)NTOK * 2 * 4);
  int*   slot_pos   = (int*)carve((size_t)NTOK * 2 * 4);
  int*   tile_meta  = (int*)carve(TILE_MAX * 4);
  int*   tile_meta2 = (int*)carve(TILE_MAX2 * 4);
  int* counts  = (int*)carve(256);
  int* offsets = (int*)carve(256);
  int* cursors = (int*)carve(256);

  if (used > ws_size) {   // guard: deterministic zero output, diagnosable
    zero_out_kernel<<<8192, 256, 0, stream>>>(out);
    return;
  }

  init_counts_kernel<<<1, 64, 0, stream>>>(counts);
  router_kernel<<<NTOK / 4, 256, 0, stream>>>(x, rw, rb, topk_idx, topk_w, counts);
  offsets_kernel<<<1, 64, 0, stream>>>(counts, offsets, cursors, tile_meta, tile_meta2);
  scatter_gather_kernel<<<NTOK, 256, 0, stream>>>(x, topk_idx, cursors, slot_pos, xg);

  transpose_conv_kernel<<<dim3(F_DIM / 64, D_DIM / 64, NEXP), 256, 0, stream>>>(
      w1, w1t, D_DIM, F_DIM);
  transpose_conv_kernel<<<dim3(D_DIM / 64, F_DIM / 64, NEXP), 256, 0, stream>>>(
      w2, w2t, F_DIM, D_DIM);

  moe_gemm1<<<TILE_MAX2 * (F_DIM / 256), 512, 0, stream>>>(
      xg, w1t, b1, counts, offsets, tile_meta2, h);
  moe_gemm2<<<TILE_MAX * (D_DIM / 128), 256, 0, stream>>>(
      h, w2t, b2, counts, offsets, tile_meta, ys);

  combine_kernel<<<NTOK, 256, 0, stream>>>(ys, slot_pos, topk_w, out);
}